// Round 6
// baseline (259.181 us; speedup 1.0000x reference)
//
#include <hip/hip_runtime.h>

typedef unsigned long long u64;
typedef unsigned int u32;

#define N_ROIS   10000
#define N_CLS    151
#define PRE_TOPN 6000
#define POST_TOPN 300
#define MAX_PER  64
#define NMS_TH   0.3f
#define SCORE_TH 0.05f

#define BLOCKA   1024
#define NWAVES   (BLOCKA / 64)   // 16
#define BANDK    1024            // band target: first band nearly always yields >=300 keeps
#define BANDCAP  1536            // band capacity (tie slack)
#define CHUNK    512             // greedy chunk (pow2 -> CWORDS=16, shift indexing)
#define CWORDS   (CHUNK / 32)    // 16
#define TROWS    10240           // scoresT padded row length

// dynamic-LDS layout (one workgroup per class):
#define SBITS_OFF 0              // u32[10000]            40000
#define KEYS_OFF  40000          // u64[1536]             12288
#define RNK_OFF   52288          // u32[1536]              6144
#define SBOX_OFF  58432          // float4[1536]          24576
#define SIDX_OFF  83008          // u32[1536]              6144
#define SUPP_OFF  89152          // u32[512*16]           32768
#define KBOX_OFF  121920         // float4[304]            4864
#define SMEM_BYTES 126784

// IoU decision, IEEE f32 (no FMA contraction: "areaa+areab-inter" would fuse and
// could flip borderline iou<=0.3 decisions vs the XLA reference).
__device__ __forceinline__ bool suppresses(float4 a, float4 b)
{
#pragma clang fp contract(off)
    float areaa = (a.z - a.x + 1.f) * (a.w - a.y + 1.f);
    float areab = (b.z - b.x + 1.f) * (b.w - b.y + 1.f);
    float ix1 = fmaxf(a.x, b.x), iy1 = fmaxf(a.y, b.y);
    float ix2 = fminf(a.z, b.z), iy2 = fminf(a.w, b.w);
    float iw = fmaxf(ix2 - ix1 + 1.f, 0.f);
    float ih = fmaxf(iy2 - iy1 + 1.f, 0.f);
    float inter = iw * ih;
    float iou = inter / (areaa + areab - inter);
    return iou > NMS_TH;
}

__global__ __launch_bounds__(BLOCKA)
void nms_kernel(const float* __restrict__ scores,
                const float* __restrict__ scoresT,
                const float* __restrict__ boxes,
                float* __restrict__ dists,
                u64* __restrict__ rowkey,
                int useT)
{
    extern __shared__ __align__(16) char smem[];
    __shared__ int s_cnts[32];          // rotating count slots (1 barrier per count)
    __shared__ int s_cc, s_nk, s_chg;
    __shared__ u32 s_redu[NWAVES];
    __shared__ u32 s_alive[CWORDS], s_rz[CWORDS];
    __shared__ u32 s_K[CWORDS], s_Supp[CWORDS];
    __shared__ int s_wpre[CWORDS];
    __shared__ int s_wofs[NWAVES + 1];  // ordered-emit wave offsets (rare path)
    __shared__ int s_resume;

    u32*    sbits = (u32*)smem;
    u64*    keys  = (u64*)(smem + KEYS_OFF);
    u32*    rnk   = (u32*)(smem + RNK_OFF);
    float4* sbox  = (float4*)(smem + SBOX_OFF);
    u32*    sidx  = (u32*)(smem + SIDX_OFF);
    u32*    supp  = (u32*)(smem + SUPP_OFF);
    float4* kbox  = (float4*)(smem + KBOX_OFF);

    const int c    = blockIdx.x + 1;    // classes 1..150 (class 0 = background, masked)
    const int tid  = threadIdx.x;
    const int lane = tid & 63, wid = tid >> 6;

    // ---- 1. score-bit column -> LDS + column max (f32 bits order-monotone for >=0)
    u32 lmax = 0;
    if (useT) {
        const float* colp = scoresT + (size_t)c * TROWS;
        for (int r = tid; r < N_ROIS; r += BLOCKA) {
            u32 b = __float_as_uint(colp[r]); sbits[r] = b; lmax = b > lmax ? b : lmax;
        }
    } else {
        for (int r = tid; r < N_ROIS; r += BLOCKA) {
            u32 b = __float_as_uint(scores[(size_t)r * N_CLS + c]); sbits[r] = b; lmax = b > lmax ? b : lmax;
        }
    }
    for (int off = 32; off; off >>= 1) { u32 o = __shfl_down(lmax, off); lmax = o > lmax ? o : lmax; }
    if (lane == 0) s_redu[wid] = lmax;
    if (tid < 32) s_cnts[tid] = 0;
    __syncthreads();
    if (tid == 0) {
        u32 m = s_redu[0];
        for (int w = 1; w < NWAVES; ++w) m = s_redu[w] > m ? s_redu[w] : m;
        s_redu[0] = m; s_nk = 0;
    }
    __syncthreads();
    if (s_redu[0] <= __float_as_uint(SCORE_TH)) return;  // col_valid false: column stays 0

    // block count of {sbits >= v}: rotating slots, ONE barrier per call
    int slot = 0;
    auto count_ge = [&](u32 v) -> int {
        int cnt = 0;
        const u64* sb2 = (const u64*)sbits;
        for (int r2 = tid; r2 < N_ROIS / 2; r2 += BLOCKA) {
            u64 two = sb2[r2];
            cnt += ((u32)two >= v) ? 1 : 0;
            cnt += ((u32)(two >> 32) >= v) ? 1 : 0;
        }
        for (int off = 32; off; off >>= 1) cnt += __shfl_down(cnt, off);
        if (lane == 0 && cnt) atomicAdd(&s_cnts[slot & 31], cnt);
        __syncthreads();
        int total = s_cnts[slot & 31];
        if (tid == 0) s_cnts[(slot + 16) & 31] = 0;
        ++slot;
        return total;
    };

    // unordered compact {vlo <= bits < vhiX} into keys[pos0..] (rank pass canonicalizes order)
    auto compactRange = [&](u32 vlo, u32 vhiX, int pos0) -> int {
        if (tid == 0) s_cc = 0;
        __syncthreads();
        for (int r = tid; r < TROWS; r += BLOCKA) {
            bool pred = (r < N_ROIS) && (sbits[r] >= vlo) && (sbits[r] < vhiX);
            u64 ball = __ballot(pred);
            int bpos = 0, bcnt = __popcll(ball);
            if (lane == 0 && bcnt) bpos = atomicAdd(&s_cc, bcnt);
            bpos = __shfl(bpos, 0);
            if (pred) {
                int pos = pos0 + bpos + (int)__popcll(ball & ((1ull << lane) - 1ull));
                if (pos < BANDCAP)
                    keys[pos] = ((u64)sbits[r] << 32) | (u64)(0xFFFFFFFFu - (u32)r);
            }
        }
        __syncthreads();
        return s_cc;
    };

    // row-ORDERED emit of {bits == v, row >= rowStart} (rare path: exact tie mass);
    // emits up to capN into keys[pos0..]; returns resume row (N_ROIS = exhausted)
    auto emitEq = [&](u32 v, int rowStart, int pos0, int capN, int* emittedOut) -> int {
        int run = 0, resume = N_ROIS;
        for (int r0 = 0; r0 < N_ROIS; r0 += BLOCKA) {
            if (r0 + BLOCKA <= rowStart) continue;       // uniform skip
            int r = r0 + tid;
            bool pred = (r < N_ROIS) && (r >= rowStart) && (sbits[r] == v);
            u64 ball = __ballot(pred);
            if (lane == 0) s_wofs[wid] = __popcll(ball);
            __syncthreads();
            if (tid == 0) {
                int acc = 0;
                for (int w = 0; w < NWAVES; ++w) { int cw = s_wofs[w]; s_wofs[w] = acc; acc += cw; }
                s_wofs[NWAVES] = acc; s_resume = N_ROIS;
            }
            __syncthreads();
            int tot = s_wofs[NWAVES];
            if (pred) {
                int idx = run + s_wofs[wid] + (int)__popcll(ball & ((1ull << lane) - 1ull));
                if (idx < capN) keys[pos0 + idx] = ((u64)v << 32) | (u64)(0xFFFFFFFFu - (u32)r);
                else atomicMin(&s_resume, r);
            }
            __syncthreads();
            if (run + tot > capN) {                      // clipped in this chunk
                resume = s_resume < (r0 + BLOCKA) ? s_resume : (r0 + BLOCKA);
                run = capN;
                break;
            }
            run += tot;
        }
        *emittedOut = run;
        return resume;
    };

    // ---- 2. lazy band loop (typical: band 0 only)
    u32 Vhi = 0x80000000u;      // exclusive upper bound of unprocessed values
    int procCnt = 0, knum = 0;
    u32 Vfloor = 0; int eligTotal = 0x7FFFFFFF; bool haveFloor = false;
    u32 eqV = 0; int eqRow = N_ROIS; bool eqPend = false;

    for (int band = 0; band < 64 && knum < POST_TOPN; ++band) {
        int C = 0;
        if (eqPend) {                                    // continue equal-value stream (rare)
            int E; int resume = emitEq(eqV, eqRow, 0, BANDCAP, &E);
            C = E; procCnt += E;
            if (resume >= N_ROIS) { eqPend = false; Vhi = eqV; }
            eqRow = resume;
            if (C == 0) { if (eqPend) break; else continue; }
        } else {
            if (band >= 1) {                             // rare: need the exact 6000-floor
                if (!haveFloor) {
                    u32 V = 0; int cv = N_ROIS;
                    for (int b = 30; b >= 0; --b) {
                        u32 cd = V | (1u << b);
                        int c2 = count_ge(cd);
                        if (c2 >= PRE_TOPN) { V = cd; cv = c2; }
                    }
                    Vfloor = V; eligTotal = cv; haveFloor = true;
                }
                if (procCnt >= eligTotal) break;         // all eligible processed
            }
            int target = procCnt + BANDK;
            int capAbs = procCnt + BANDCAP;
            u32 V = 0; int cv = N_ROIS;
            for (int b = 30; b >= 16; --b) {             // 15-round 16-bit-granular select
                u32 cd = V | (1u << b);
                int c2 = count_ge(cd);
                if (c2 >= target) { V = cd; cv = c2; }
            }
            for (int b = 15; b >= 0 && cv > capAbs; --b) {  // rare refinement
                u32 cd = V | (1u << b);
                int c2 = count_ge(cd);
                if (c2 >= target) { V = cd; cv = c2; }
            }
            if (haveFloor && V < Vfloor) { V = Vfloor; cv = eligTotal; }
            if (cv > capAbs) {                           // exact-duplicate mass: gt + eq stream
                int ngt = compactRange(V + 1, Vhi, 0);
                int E; int resume = emitEq(V, 0, ngt, BANDCAP - ngt, &E);
                C = ngt + E; procCnt += C;
                eqV = V; eqRow = resume; eqPend = (resume < N_ROIS);
                if (!eqPend) Vhi = V;
            } else {
                C = compactRange(V, Vhi, 0);
                procCnt = cv; Vhi = V;
            }
            if (C <= 0) continue;
        }

        // ---- 3. exact rank by pairwise comparison (keys unique -> exact permutation)
        for (int q = tid; q < BANDCAP; q += BLOCKA) rnk[q] = 0;
        __syncthreads();
        {
            int q0 = tid >> 1, par = tid & 1;
            for (int q = q0; q < C; q += BLOCKA / 2) {
                u64 kq = keys[q]; int partial = 0;
                for (int p = par; p < C; p += 2) partial += (keys[p] > kq) ? 1 : 0;
                atomicAdd(&rnk[q], (u32)partial);
            }
        }
        __syncthreads();
        // scatter into sorted order + gather candidate boxes
        for (int q = tid; q < C; q += BLOCKA) {
            u64 kq = keys[q];
            u32 pos = rnk[q];
            u32 r = 0xFFFFFFFFu - (u32)kq;
            sidx[pos] = r;
            sbox[pos] = *(const float4*)(boxes + ((size_t)r * N_CLS + c) * 4);
        }
        __syncthreads();

        // ---- 4. chunked greedy: phase A (vs kept) -> pair matrix -> Jacobi fixpoint
        for (int base = 0; base < C && knum < POST_TOPN; base += CHUNK) {
            int chunkN = (C - base) < CHUNK ? (C - base) : CHUNK;
            int knum0 = knum;

            if (tid < CHUNK) {          // phase A (knum0==0 on chunk 0 of band 0 -> trivial)
                bool al = false;
                if (tid < chunkN) {
                    al = true;
                    float4 bq = sbox[base + tid];
                    for (int j = 0; j < knum0; ++j)
                        if (suppresses(kbox[j], bq)) { al = false; break; }
                }
                u64 ball = __ballot(al);
                if (lane == 0) { s_alive[wid * 2] = (u32)ball; s_alive[wid * 2 + 1] = (u32)(ball >> 32); }
            }
            if (tid < CWORDS) s_rz[tid] = 0;
            for (int w = tid; w < CHUNK * CWORDS; w += BLOCKA) supp[w] = 0;
            __syncthreads();

            {   // build "p suppresses q" (p<q, both alive); 2 threads per row q; broadcast reads
                int q0 = tid >> 1, par = tid & 1;
                if (q0 < chunkN && ((s_alive[q0 >> 5] >> (q0 & 31)) & 1u)) {
                    float4 bq = sbox[base + q0];
                    for (int p = par; p < q0; p += 2) {
                        if (!((s_alive[p >> 5] >> (p & 31)) & 1u)) continue;
                        if (suppresses(sbox[base + p], bq)) {
                            atomicOr(&supp[(p << 4) + (q0 >> 5)], 1u << (q0 & 31));
                            atomicOr(&s_rz[p >> 5], 1u << (p & 31));
                        }
                    }
                }
            }
            if (tid < CWORDS) s_K[tid] = 0;   // will be set below; placed to share barrier
            __syncthreads();

            // ---- Jacobi fixpoint: keep[q] = alive[q] & !exists(p<q kept, S[p][q])
            // start optimistic K=alive; converges in (max chain depth)+1 iterations
            if (tid < CWORDS) s_K[tid] = s_alive[tid];
            for (;;) {
                __syncthreads();                   // (A) everyone read s_chg / K stable
                if (tid < CWORDS) s_Supp[tid] = 0;
                if (tid == 0) s_chg = 0;
                __syncthreads();                   // (B)
                for (int pw = tid; pw < (chunkN << 4); pw += BLOCKA) {
                    int p = pw >> 4, w = pw & 15;
                    if (((s_rz[p >> 5] >> (p & 31)) & 1u) &&
                        ((s_K[p >> 5] >> (p & 31)) & 1u)) {
                        u32 rw = supp[(p << 4) + w];
                        if (rw) atomicOr(&s_Supp[w], rw);
                    }
                }
                __syncthreads();                   // (C)
                if (tid < CWORDS) {
                    u32 nk = s_alive[tid] & ~s_Supp[tid];
                    if (nk != s_K[tid]) { s_K[tid] = nk; atomicOr(&s_chg, 1); }
                }
                __syncthreads();                   // (D)
                if (!s_chg) break;
            }

            // truncate to first (POST_TOPN - knum0) keeps; build word prefix for commit ranks
            if (wid == 0) {
                u32 kw = (lane < CWORDS) ? s_K[lane] : 0u;
                int pc = __popc(kw);
                int inc = pc;
                for (int off = 1; off < 32; off <<= 1) { int o = __shfl_up(inc, off); if (lane >= off) inc += o; }
                int ex = inc - pc;
                int budget = POST_TOPN - knum0;    // >= 1
                u32 fin = kw;
                if (ex >= budget) fin = 0;
                else {
                    int need = budget - ex;
                    if (pc > need) {
                        while (__popc(fin) > need) fin &= ~(1u << (31 - __clz(fin)));
                    }
                }
                int pc2 = __popc(fin);
                int inc2 = pc2;
                for (int off = 1; off < 32; off <<= 1) { int o = __shfl_up(inc2, off); if (lane >= off) inc2 += o; }
                if (lane < CWORDS) { s_K[lane] = fin; s_wpre[lane] = inc2 - pc2; }
                if (lane == CWORDS - 1) s_nk = knum0 + inc2;
            }
            __syncthreads();

            // commit: truncated K mask IS the kept set for this chunk
            if (tid < CHUNK) {
                int w = tid >> 5, b = tid & 31;
                u32 word = s_K[w];
                if ((word >> b) & 1u) {
                    int rank = knum0 + s_wpre[w] + __popc(word & ((1u << b) - 1u));
                    int q = base + tid;
                    u32 r = sidx[q];
                    u32 sb = sbits[r];
                    kbox[rank] = sbox[q];
                    dists[(size_t)r * N_CLS + c] = __uint_as_float(sb);
                    atomicMax(rowkey + r, ((u64)sb << 32) | (u64)(0xFFFFFFFFu - (u32)c));
                }
            }
            __syncthreads();
            knum = s_nk;
        }
    }
}

// fused: scores transpose (coalesced column reads for nms) + zero dists/rowkey
__global__ __launch_bounds__(1024)
void transpose_zero_kernel(const float* __restrict__ in, float* __restrict__ outT,
                           float* __restrict__ dists, u64* __restrict__ rowkey, int useT)
{
    __shared__ float tile[32][33];
    if (useT) {
        int tx = threadIdx.x & 31, ty = threadIdx.x >> 5;
        int rb = blockIdx.x * 32, cb = blockIdx.y * 32;
        int r = rb + ty, cc = cb + tx;
        tile[ty][tx] = (r < N_ROIS && cc < N_CLS) ? in[(size_t)r * N_CLS + cc] : 0.f;
        __syncthreads();
        int oc = cb + ty, orr = rb + tx;
        if (oc < N_CLS) outT[(size_t)oc * TROWS + orr] = tile[tx][ty];
    }
    int bid = blockIdx.y * gridDim.x + blockIdx.x;   // 0..1599
    int flat = bid * 1024 + threadIdx.x;             // covers 1638400 >= 1510000
    if (flat < N_ROIS * N_CLS) dists[flat] = 0.f;
    if (flat < N_ROIS) rowkey[flat] = 0ull;
}

// top-64: 15-round bit-greedy select + compact + register rank (no serial argmaxes)
__global__ __launch_bounds__(BLOCKA)
void topk_kernel(const u64* __restrict__ rowkey, float* __restrict__ out)
{
    __shared__ u32 shi[N_ROIS];
    __shared__ int s_cnts[32];
    __shared__ int s_cc;
    __shared__ u64 cand[192];
    __shared__ int s_wofs[NWAVES + 1];
    const int tid = threadIdx.x, lane = tid & 63, wid = tid >> 6;

    if (tid < 32) s_cnts[tid] = 0;
    if (tid == 0) s_cc = 0;
    if (tid < 192) cand[tid] = 0;
    for (int i = tid; i < N_ROIS; i += BLOCKA) {
        u64 rk = rowkey[i];
        u32 hb = (u32)(rk >> 32);
        shi[i] = (__uint_as_float(hb) > SCORE_TH) ? hb : 0u;   // invalid rows -> 0
    }
    __syncthreads();

    int slot = 0;
    auto count_ge = [&](u32 v) -> int {
        int cnt = 0;
        const u64* s2 = (const u64*)shi;
        for (int r2 = tid; r2 < N_ROIS / 2; r2 += BLOCKA) {
            u64 two = s2[r2];
            cnt += ((u32)two >= v) ? 1 : 0;
            cnt += ((u32)(two >> 32) >= v) ? 1 : 0;
        }
        for (int off = 32; off; off >>= 1) cnt += __shfl_down(cnt, off);
        if (lane == 0 && cnt) atomicAdd(&s_cnts[slot & 31], cnt);
        __syncthreads();
        int total = s_cnts[slot & 31];
        if (tid == 0) s_cnts[(slot + 16) & 31] = 0;
        ++slot;
        return total;
    };

    const int cap = 128;
    u32 V = 0; int cv = N_ROIS;
    for (int b = 30; b >= 16; --b) {
        u32 cd = V | (1u << b);
        int c2 = count_ge(cd);
        if (c2 >= MAX_PER) { V = cd; cv = c2; }
    }
    for (int b = 15; b >= 0 && cv > cap; --b) {   // rare refinement
        u32 cd = V | (1u << b);
        int c2 = count_ge(cd);
        if (c2 >= MAX_PER) { V = cd; cv = c2; }
    }
    if (V == 0) { V = 1; cv = count_ge(1); }      // fewer than 64 valid rows
    int C = 0;
    if (cv > cap) {
        // exact-duplicate fallback: strictly-greater part + lowest-row equal fill to 64
        if (tid == 0) s_cc = 0;
        __syncthreads();
        for (int i = tid; i < TROWS; i += BLOCKA) {
            bool pred = (i < N_ROIS) && (shi[i] >= V + 1);
            u64 ball = __ballot(pred);
            int bpos = 0, bcnt = __popcll(ball);
            if (lane == 0 && bcnt) bpos = atomicAdd(&s_cc, bcnt);
            bpos = __shfl(bpos, 0);
            if (pred) {
                int pos = bpos + (int)__popcll(ball & ((1ull << lane) - 1ull));
                if (pos < cap) cand[pos] = ((u64)shi[i] << 32) | (u64)(0xFFFFFFFFu - (u32)i);
            }
        }
        __syncthreads();
        int ngt = s_cc; if (ngt > cap) ngt = cap;
        int need = MAX_PER - ngt;                  // > 0 here
        int run = 0;
        for (int r0 = 0; r0 < N_ROIS && run < need; r0 += BLOCKA) {
            int r = r0 + tid;
            bool pred = (r < N_ROIS) && (shi[r] == V);
            u64 ball = __ballot(pred);
            if (lane == 0) s_wofs[wid] = __popcll(ball);
            __syncthreads();
            if (tid == 0) {
                int acc = 0;
                for (int w = 0; w < NWAVES; ++w) { int cw = s_wofs[w]; s_wofs[w] = acc; acc += cw; }
                s_wofs[NWAVES] = acc;
            }
            __syncthreads();
            int tot = s_wofs[NWAVES];
            if (pred) {
                int idx = run + s_wofs[wid] + (int)__popcll(ball & ((1ull << lane) - 1ull));
                if (idx < need) cand[ngt + idx] = ((u64)V << 32) | (u64)(0xFFFFFFFFu - (u32)r);
            }
            __syncthreads();
            run += tot;
        }
        C = ngt + (run < need ? run : need);
    } else {
        if (tid == 0) s_cc = 0;
        __syncthreads();
        for (int i = tid; i < TROWS; i += BLOCKA) {
            bool pred = (i < N_ROIS) && (shi[i] >= V);
            u64 ball = __ballot(pred);
            int bpos = 0, bcnt = __popcll(ball);
            if (lane == 0 && bcnt) bpos = atomicAdd(&s_cc, bcnt);
            bpos = __shfl(bpos, 0);
            if (pred) {
                int pos = bpos + (int)__popcll(ball & ((1ull << lane) - 1ull));
                if (pos < cap) cand[pos] = ((u64)shi[i] << 32) | (u64)(0xFFFFFFFFu - (u32)i);
            }
        }
        __syncthreads();
        C = s_cc; if (C > cap) C = cap;
    }

    float* out_s = out + (size_t)N_ROIS * N_CLS;
    float* out_i = out_s + MAX_PER;
    float* out_l = out_i + MAX_PER;

    int myrank = -1; u64 myk = 0;
    if (tid < C) {
        myk = cand[tid];
        myrank = 0;
        for (int p = 0; p < C; ++p) myrank += (cand[p] > myk) ? 1 : 0;   // keys unique
    }
    if (tid < MAX_PER) { out_s[tid] = 0.f; out_i[tid] = -1.f; out_l[tid] = -1.f; }
    __syncthreads();
    if (tid < C && myrank < MAX_PER) {
        u32 r = 0xFFFFFFFFu - (u32)myk;
        out_s[myrank] = __uint_as_float((u32)(myk >> 32));
        out_i[myrank] = (float)r;
        out_l[myrank] = (float)(0xFFFFFFFFu - (u32)rowkey[r]);   // label from rowkey low word
    }
}

extern "C" void kernel_launch(void* const* d_in, const int* in_sizes, int n_in,
                              void* d_out, int out_size, void* d_ws, size_t ws_size,
                              hipStream_t stream)
{
    const float* scores = (const float*)d_in[0];  // [10000, 151] f32
    const float* boxes  = (const float*)d_in[1];  // [10000, 151, 4] f32
    float* out = (float*)d_out;                   // dists[1510000] | scores[64] | inds[64] | labels[64]
    u64* rowkey = (u64*)d_ws;                     // [10000] packed (scorebits<<32)|~class

    size_t needT = 80000 + (size_t)N_CLS * TROWS * sizeof(float);
    int useT = (ws_size >= needT) ? 1 : 0;
    float* scoresT = (float*)((char*)d_ws + 80000);

    (void)hipFuncSetAttribute((const void*)nms_kernel,
                              hipFuncAttributeMaxDynamicSharedMemorySize, SMEM_BYTES);

    transpose_zero_kernel<<<dim3(320, 5), 1024, 0, stream>>>(scores, scoresT, out, rowkey, useT);
    nms_kernel<<<N_CLS - 1, BLOCKA, SMEM_BYTES, stream>>>(scores, scoresT, boxes, out, rowkey, useT);
    topk_kernel<<<1, BLOCKA, 0, stream>>>(rowkey, out);
}